// Round 7
// baseline (3067.262 us; speedup 1.0000x reference)
//
#include <hip/hip_runtime.h>
#include <hip/hip_bf16.h>
#include <hip/hip_fp16.h>
#include <cmath>

typedef __attribute__((ext_vector_type(8))) short short8_t;
typedef __attribute__((ext_vector_type(4))) float f32x4;

static __device__ __forceinline__ short f2bs(float f) {
    union { __hip_bfloat16 h; short s; } u;
    u.h = __float2bfloat16(f);
    return u.s;
}
static __device__ __forceinline__ float bs2f(unsigned int us) {
    union { float f; unsigned int i; } u;
    u.i = us << 16;
    return u.f;
}
static __device__ __forceinline__ unsigned int pack2bf(float a, float b) {
    return (unsigned int)(unsigned short)f2bs(a) |
           ((unsigned int)(unsigned short)f2bs(b) << 16);
}
// Barrier that waits only on LDS ops (lgkmcnt), NOT vmem: atomics/gathers keep
// flowing across it. All inter-wave deps in these kernels are LDS-only.
static __device__ __forceinline__ void lds_barrier() {
    asm volatile("s_waitcnt lgkmcnt(0)\n\ts_barrier" ::: "memory");
}

// ---------------------------------------------------------------------------
// Pack kernel: Wd/W1/W2 -> bf16 MFMA B-fragment order; M = W0t @ We (fp32).
// ---------------------------------------------------------------------------
__global__ void pack_kernel(const float* __restrict__ Wd,
                            const float* __restrict__ W1,
                            const float* __restrict__ W2,
                            const float* __restrict__ W0,
                            const float* __restrict__ We,
                            short* __restrict__ pWd,
                            short* __restrict__ pW1,
                            short* __restrict__ pW2,
                            float* __restrict__ Mb)
{
    const int tid = blockIdx.x * blockDim.x + threadIdx.x;
    const int stride = gridDim.x * blockDim.x;
    for (int i = tid; i < 6 * 32768; i += stride) {
        int c = i >> 15, rem = i & 32767;
        int f = rem >> 9, l = (rem >> 3) & 63, j = rem & 7;
        int kk = f >> 4, nt = f & 15;
        int k = kk * 32 + (l >> 4) * 8 + j;
        int n = nt * 16 + (l & 15);
        pWd[i] = f2bs(Wd[(size_t)c * 32768 + k * 256 + n]);
    }
    for (int i = tid; i < 6 * 16384; i += stride) {
        int c = i >> 14, rem = i & 16383;
        int f = rem >> 9, l = (rem >> 3) & 63, j = rem & 7;
        int kk = f >> 3, nt = f & 7;
        int k = kk * 32 + (l >> 4) * 8 + j;
        int n = nt * 16 + (l & 15);
        pW1[i] = f2bs(W1[(size_t)c * 16384 + k * 128 + n]);
        pW2[i] = f2bs(W2[(size_t)c * 16384 + k * 128 + n]);
    }
    for (int i = tid; i < 6 * 512; i += stride) {
        int c = i >> 9, rem = i & 511;
        int a = rem >> 7, h = rem & 127;
        int t = c % 3;
        float m = 0.f;
        #pragma unroll
        for (int j = 0; j < 4; ++j)
            m = fmaf(W0[t * 16 + a * 4 + j], We[(size_t)c * 512 + j * 128 + h], m);
        Mb[i] = m;
    }
}

// ---------------------------------------------------------------------------
// Convert fp32 -> bf16 (two arrays)
// ---------------------------------------------------------------------------
__global__ void tobf16_kernel(const float* __restrict__ a, const float* __restrict__ b,
                              unsigned short* __restrict__ oa, unsigned short* __restrict__ ob,
                              int n4)
{
    int i = blockIdx.x * blockDim.x + threadIdx.x;
    const int stride = gridDim.x * blockDim.x;
    for (; i < n4; i += stride) {
        float4 va = ((const float4*)a)[i];
        uint2 pa; pa.x = pack2bf(va.x, va.y); pa.y = pack2bf(va.z, va.w);
        ((uint2*)oa)[i] = pa;
        float4 vb = ((const float4*)b)[i];
        uint2 pb; pb.x = pack2bf(vb.x, vb.y); pb.y = pack2bf(vb.z, vb.w);
        ((uint2*)ob)[i] = pb;
    }
}

// ---------------------------------------------------------------------------
// Edge kernel (persistent, 512 threads / 8 waves, 64 edges/tile).
// Wave w owns output cols [32w, 32w+32) (nt = 2w, 2w+1) AND flush rows
// [8w, 8w+8) — so xj stays in registers (no sXj LDS).
// Phase A: rbf (k-slice [16w,16w+16)) -> sRbf; xj -> regs.      bar1
// Phase B: next-tile meta prefetch; GEMM; acc+bd -> sSS (fp16);
//          next-tile gathers.                                   bar2
// Phase C: msg = relu(xj*scale+shift) from sSS; fp16x2 atomics (issued last).
// LDS 48KB: sRbf 16KB + sSS 32KB. Target: VGPR<=128 -> 16 waves/CU.
// ---------------------------------------------------------------------------
__global__ __launch_bounds__(512, 4)
void edge_mfma_kernel(
    const unsigned short* __restrict__ xsb,   // bf16 x_src (N,128)
    const int* __restrict__ ei,
    const float* __restrict__ ew, const float* __restrict__ ea,
    const short* __restrict__ pWd, const float* __restrict__ bd,
    const float* __restrict__ Mb, const float* __restrict__ be,
    __half2* __restrict__ agg, int E, int ntiles,
    float rs, float rstep, float rbeta)
{
    __shared__ short sRbf[64 * 128];   // bf16, swizzled [edge][k], 16KB
    __shared__ __half sSS[64 * 256];   // fp16, swizzled [edge][col], 32KB

    const int t = threadIdx.x;
    const int lane = t & 63;
    const int w = t >> 6;          // 0..7
    const int l15 = lane & 15;
    const int l4 = lane >> 4;

    // --- per-block constants ---
    short8_t bfrag[4][2];          // [kk][i], nt = 2w+i
    #pragma unroll
    for (int kk = 0; kk < 4; ++kk)
        #pragma unroll
        for (int i = 0; i < 2; ++i)
            bfrag[kk][i] = *(const short8_t*)&pWd[((kk * 16 + 2 * w + i) * 64 + lane) * 8];
    float bdv[2];
    #pragma unroll
    for (int i = 0; i < 2; ++i) bdv[i] = bd[(2 * w + i) * 16 + l15];
    const float be0 = be[2 * lane], be1 = be[2 * lane + 1];
    float ma0[4], ma1[4];
    #pragma unroll
    for (int a = 0; a < 4; ++a) {
        ma0[a] = Mb[a * 128 + 2 * lane];
        ma1[a] = Mb[a * 128 + 2 * lane + 1];
    }

    const int stride = gridDim.x;
    int tile = blockIdx.x;
    if (tile >= ntiles) return;

    // ---- prologue: meta + gathers for first tile ----
    float dd_c; int dst_c; float4 ea_c;
    unsigned int gx[8];
    {
        const int e0 = tile << 6;
        int eL = e0 + lane;
        int eLc = eL < E ? eL : E - 1;
        dd_c = ew[eLc];
        int es = e0 + w * 8 + (lane & 7);
        int esv = es < E ? es : E - 1;
        dst_c = (es < E) ? ei[E + esv] : -1;
        int src_c = ei[esv];
        ea_c = *(const float4*)&ea[(size_t)esv * 4];
        #pragma unroll
        for (int r = 0; r < 8; ++r) {
            int srn = __shfl(src_c, r);
            gx[r] = *(const unsigned int*)&xsb[(size_t)srn * 128 + lane * 2];
        }
    }

    for (; tile < ntiles; tile += stride) {
        // ---- phase A: rbf -> sRbf (k-slice), xj -> regs ----
        const float edv = __expf(-dd_c);
        const float dcc = fminf(dd_c, 5.0f);
        const float cutv = 0.5f * (__cosf(dcc * 0.62831853071795864769f) + 1.0f);
        {
            char* base = (char*)sRbf + lane * 256;
            #pragma unroll
            for (int c = 0; c < 2; ++c) {
                short8_t v;
                #pragma unroll
                for (int j = 0; j < 8; ++j) {
                    float mean = rs + (float)(w * 16 + c * 8 + j) * rstep;
                    float diff = edv - mean;
                    v[j] = f2bs(cutv * __expf(-rbeta * diff * diff));
                }
                *(short8_t*)(base + ((w * 32 + c * 16) ^ ((lane & 7) << 4))) = v;
            }
        }
        unsigned int xjr[8];
        #pragma unroll
        for (int r = 0; r < 8; ++r) {
            float ea0 = __shfl(ea_c.x, r), ea1 = __shfl(ea_c.y, r);
            float ea2 = __shfl(ea_c.z, r), ea3 = __shfl(ea_c.w, r);
            unsigned int g = gx[r];
            float x0 = bs2f(g & 0xffffu), x1 = bs2f(g >> 16);
            float o0 = x0 + be0 + ea0 * ma0[0] + ea1 * ma0[1] + ea2 * ma0[2] + ea3 * ma0[3];
            float o1 = x1 + be1 + ea0 * ma1[0] + ea1 * ma1[1] + ea2 * ma1[2] + ea3 * ma1[3];
            xjr[r] = pack2bf(o0, o1);
        }

        lds_barrier();   // bar1: sRbf visible (also fences prev-tile sSS reads)

        // ---- phase B ----
        const int ntile = tile + stride;
        const bool has_next = ntile < ntiles;
        float dd_n = 0.f; int dst_n = -1; int src_n = 0;
        float4 ea_n = {0.f, 0.f, 0.f, 0.f};
        if (has_next) {   // issue next-tile meta loads before any atomics
            const int e0n = ntile << 6;
            int eL = e0n + lane;
            int eLc = eL < E ? eL : E - 1;
            dd_n = ew[eLc];
            int es = e0n + w * 8 + (lane & 7);
            int esv = es < E ? es : E - 1;
            dst_n = (es < E) ? ei[E + esv] : -1;
            src_n = ei[esv];
            ea_n = *(const float4*)&ea[(size_t)esv * 4];
        }
        __builtin_amdgcn_sched_barrier(0);   // pin prefetch issue before GEMM

        // GEMM: ss(64 x 32cols/wave) = rbf(64x128) @ Wd-slice
        f32x4 acc[4][2];
        #pragma unroll
        for (int m = 0; m < 4; ++m) {
            acc[m][0] = (f32x4){0.f, 0.f, 0.f, 0.f};
            acc[m][1] = (f32x4){0.f, 0.f, 0.f, 0.f};
        }
        #pragma unroll
        for (int kk = 0; kk < 4; ++kk) {
            short8_t af[4];
            #pragma unroll
            for (int m = 0; m < 4; ++m) {
                int row = m * 16 + l15;
                int byte = row * 256 + ((kk * 64 + l4 * 16) ^ ((row & 7) << 4));
                af[m] = *(const short8_t*)((const char*)sRbf + byte);
            }
            #pragma unroll
            for (int m = 0; m < 4; ++m)
                #pragma unroll
                for (int i = 0; i < 2; ++i)
                    acc[m][i] = __builtin_amdgcn_mfma_f32_16x16x32_bf16(
                        af[m], bfrag[kk][i], acc[m][i], 0, 0, 0);
        }

        // ss = acc + bd -> sSS fp16 (swizzled [edge][col])
        #pragma unroll
        for (int m = 0; m < 4; ++m)
            #pragma unroll
            for (int i = 0; i < 2; ++i) {
                int col = (2 * w + i) * 16 + l15;
                #pragma unroll
                for (int r = 0; r < 4; ++r) {
                    int row = m * 16 + l4 * 4 + r;
                    int byte = row * 512 + ((col * 2) ^ ((row & 7) << 4));
                    *(__half*)((char*)sSS + byte) = __float2half(acc[m][i][r] + bdv[i]);
                }
            }

        // issue next-tile gathers (acc dead; still before atomics)
        if (has_next) {
            #pragma unroll
            for (int r = 0; r < 8; ++r) {
                int srn = __shfl(src_n, r);
                gx[r] = *(const unsigned int*)&xsb[(size_t)srn * 128 + lane * 2];
            }
        }
        const int dst_f = dst_c;
        dd_c = dd_n; dst_c = dst_n; ea_c = ea_n;

        lds_barrier();   // bar2: sSS visible; sRbf GEMM reads done

        // ---- phase C: msg + fp16x2 atomics (own rows [8w,8w+8)) ----
        #pragma unroll
        for (int r = 0; r < 8; ++r) {
            int e = 8 * w + r;
            int dst = __shfl(dst_f, r);
            unsigned int sc = *(const unsigned int*)
                ((const char*)sSS + e * 512 + ((lane * 4) ^ ((e & 7) << 4)));
            unsigned int sh = *(const unsigned int*)
                ((const char*)sSS + e * 512 + ((256 + lane * 4) ^ ((e & 7) << 4)));
            float2 scf = __half22float2(*(const __half2*)&sc);
            float2 shf = __half22float2(*(const __half2*)&sh);
            unsigned int g = xjr[r];
            float x0 = bs2f(g & 0xffffu), x1 = bs2f(g >> 16);
            float m0 = fmaxf(fmaf(x0, scf.x, shf.x), 0.0f);
            float m1 = fmaxf(fmaf(x1, scf.y, shf.y), 0.0f);
            __half2 hv = __floats2half2_rn(m0, m1);
            unsigned int hbits = *(unsigned int*)&hv;
            // skip exact-zero messages (agg only holds {+0, positive})
            if (dst >= 0 && hbits != 0u)
                unsafeAtomicAdd(agg + (size_t)dst * 64 + lane, hv);
        }
    }
}

// ---------------------------------------------------------------------------
// Node kernel (persistent): out = relu((agg+x)@W1+b1)@W2+b2 (+prev, relu opt)
// agg fp16; x_dst fp32 OR bf16; out fp32 OR bf16. 2 lgkm-barriers per tile.
// ---------------------------------------------------------------------------
__global__ __launch_bounds__(256)
void node_mfma_kernel(
    const __half2* __restrict__ agg,
    const float* __restrict__ xdf, const unsigned short* __restrict__ xdb,
    const short* __restrict__ pW1, const float* __restrict__ b1,
    const short* __restrict__ pW2, const float* __restrict__ b2,
    float* __restrict__ outf, unsigned short* __restrict__ outb,
    int N, int ntiles, int accumulate, int relu_out)
{
    __shared__ short sA[64 * 128];
    __shared__ short sH[64 * 128];

    const int t = threadIdx.x;
    const int lane = t & 63;
    const int w = t >> 6;
    const int l15 = lane & 15;
    const int l4 = lane >> 4;

    short8_t w1f[4][2], w2f[4][2];
    #pragma unroll
    for (int kk = 0; kk < 4; ++kk)
        #pragma unroll
        for (int p = 0; p < 2; ++p) {
            int nt = 2 * w + p;
            w1f[kk][p] = *(const short8_t*)&pW1[((kk * 8 + nt) * 64 + lane) * 8];
            w2f[kk][p] = *(const short8_t*)&pW2[((kk * 8 + nt) * 64 + lane) * 8];
        }
    float b1v[2], b2v[2];
    #pragma unroll
    for (int p = 0; p < 2; ++p) {
        int col = (2 * w + p) * 16 + l15;
        b1v[p] = b1[col];
        b2v[p] = b2[col];
    }

    for (int tile = blockIdx.x; tile < ntiles; tile += gridDim.x) {
        const int n0 = tile << 6;
        // --- stage A = bf16(fp16 agg + x_dst) ---
        #pragma unroll
        for (int i = 0; i < 4; ++i) {
            int idx = i * 256 + t;          // 64 rows x 16 chunks of 8 cols
            int row = idx >> 4, c8 = idx & 15;
            int gr = n0 + row; if (gr >= N) gr = N - 1;
            union { float4 f; __half2 h[4]; } ar;
            ar.f = ((const float4*)agg)[(size_t)gr * 16 + c8];
            float xv[8];
            if (xdf) {
                float4 x0 = ((const float4*)xdf)[(size_t)gr * 32 + c8 * 2];
                float4 x1 = ((const float4*)xdf)[(size_t)gr * 32 + c8 * 2 + 1];
                xv[0] = x0.x; xv[1] = x0.y; xv[2] = x0.z; xv[3] = x0.w;
                xv[4] = x1.x; xv[5] = x1.y; xv[6] = x1.z; xv[7] = x1.w;
            } else {
                uint4 xr = ((const uint4*)xdb)[(size_t)gr * 16 + c8];
                xv[0] = bs2f(xr.x & 0xffffu); xv[1] = bs2f(xr.x >> 16);
                xv[2] = bs2f(xr.y & 0xffffu); xv[3] = bs2f(xr.y >> 16);
                xv[4] = bs2f(xr.z & 0xffffu); xv[5] = bs2f(xr.z >> 16);
                xv[6] = bs2f(xr.w & 0xffffu); xv[7] = bs2f(xr.w >> 16);
            }
            short8_t v;
            #pragma unroll
            for (int j = 0; j < 4; ++j) {
                float2 a2 = __half22float2(ar.h[j]);
                v[2 * j]     = f2bs(a2.x + xv[2 * j]);
                v[2 * j + 1] = f2bs(a2.y + xv[2 * j + 1]);
            }
            int byte = row * 256 + ((c8 * 16) ^ ((row & 7) << 4));
            *(short8_t*)((char*)sA + byte) = v;
        }
        lds_barrier();

        // --- GEMM1 ---
        f32x4 acc[4][2];
        #pragma unroll
        for (int m = 0; m < 4; ++m) {
            acc[m][0] = (f32x4){0.f, 0.f, 0.f, 0.f};
            acc[m][1] = (f32x4){0.f, 0.f, 0.f, 0.f};
        }
        #pragma unroll
        for (int kk = 0; kk < 4; ++kk) {
            short8_t af[4];
            #pragma unroll
            for (int m = 0; m < 4; ++m) {
                int row = m * 16 + l15;
                int byte = row * 256 + ((kk * 64 + l4 * 16) ^ ((row & 7) << 4));
                af[m] = *(const short8_t*)((const char*)sA + byte);
            }
            #pragma unroll
            for (int m = 0; m < 4; ++m)
                #pragma unroll
                for (int p = 0; p < 2; ++p)
                    acc[m][p] = __builtin_amdgcn_mfma_f32_16x16x32_bf16(
                        af[m], w1f[kk][p], acc[m][p], 0, 0, 0);
        }
        #pragma unroll
        for (int m = 0; m < 4; ++m)
            #pragma unroll
            for (int p = 0; p < 2; ++p) {
                int col = (2 * w + p) * 16 + l15;
                #pragma unroll
                for (int r = 0; r < 4; ++r) {
                    int row = m * 16 + l4 * 4 + r;
                    short hs = f2bs(fmaxf(acc[m][p][r] + b1v[p], 0.f));
                    int byte = row * 256 + ((col * 2) ^ ((row & 7) << 4));
                    *(short*)((char*)sH + byte) = hs;
                }
            }
        lds_barrier();

        // --- GEMM2 ---
        f32x4 acc2[4][2];
        #pragma unroll
        for (int m = 0; m < 4; ++m) {
            acc2[m][0] = (f32x4){0.f, 0.f, 0.f, 0.f};
            acc2[m][1] = (f32x4){0.f, 0.f, 0.f, 0.f};
        }
        #pragma unroll
        for (int kk = 0; kk < 4; ++kk) {
            short8_t af[4];
            #pragma unroll
            for (int m = 0; m < 4; ++m) {
                int row = m * 16 + l15;
                int byte = row * 256 + ((kk * 64 + l4 * 16) ^ ((row & 7) << 4));
                af[m] = *(const short8_t*)((const char*)sH + byte);
            }
            #pragma unroll
            for (int m = 0; m < 4; ++m)
                #pragma unroll
                for (int p = 0; p < 2; ++p)
                    acc2[m][p] = __builtin_amdgcn_mfma_f32_16x16x32_bf16(
                        af[m], w2f[kk][p], acc2[m][p], 0, 0, 0);
        }
        // --- epilogue ---
        #pragma unroll
        for (int m = 0; m < 4; ++m)
            #pragma unroll
            for (int p = 0; p < 2; ++p) {
                int col = (2 * w + p) * 16 + l15;
                #pragma unroll
                for (int r = 0; r < 4; ++r) {
                    int row = n0 + m * 16 + l4 * 4 + r;
                    if (row < N) {
                        float v = acc2[m][p][r] + b2v[p];
                        if (outf) {
                            float* op = &outf[(size_t)row * 128 + col];
                            if (accumulate) v += *op;
                            if (relu_out) v = fmaxf(v, 0.f);
                            *op = v;
                        } else {
                            unsigned short* op = &outb[(size_t)row * 128 + col];
                            if (accumulate) v += bs2f((unsigned int)*op);
                            if (relu_out) v = fmaxf(v, 0.f);
                            *op = (unsigned short)f2bs(v);
                        }
                    }
                }
            }
    }
}

// ---------------------------------------------------------------------------
extern "C" void kernel_launch(void* const* d_in, const int* in_sizes, int n_in,
                              void* d_out, int out_size, void* d_ws, size_t ws_size,
                              hipStream_t stream)
{
    const float* x_lig   = (const float*)d_in[0];
    const float* x_pock  = (const float*)d_in[1];
    const int*   ei_bond = (const int*)d_in[2];
    const float* ew_bond = (const float*)d_in[3];
    const float* ea_bond = (const float*)d_in[4];
    const int*   ei_lp   = (const int*)d_in[5];
    const float* ew_lp   = (const float*)d_in[6];
    const float* ea_lp   = (const float*)d_in[7];
    const int*   ei_pl   = (const int*)d_in[8];
    const float* ew_pl   = (const float*)d_in[9];
    const float* ea_pl   = (const float*)d_in[10];
    const float* W0 = (const float*)d_in[11];
    const float* Wd = (const float*)d_in[12];
    const float* bd = (const float*)d_in[13];
    const float* We = (const float*)d_in[14];
    const float* be = (const float*)d_in[15];
    const float* W1 = (const float*)d_in[16];
    const float* b1 = (const float*)d_in[17];
    const float* W2 = (const float*)d_in[18];
    const float* b2 = (const float*)d_in[19];

    const int H = 128;
    const int N = in_sizes[0] / H;
    const int E_bond = in_sizes[3];
    const int E_lp   = in_sizes[6];
    const int E_pl   = in_sizes[9];

    // workspace: A,B,C bf16 activations; agg fp16; packed weights
    unsigned short* A  = (unsigned short*)d_ws;           // x_lig_bf -> lig0_bf
    unsigned short* Bb = A  + (size_t)N * H;              // x_pock_bf
    unsigned short* C  = Bb + (size_t)N * H;              // pock0_bf
    __half* agg = (__half*)(C + (size_t)N * H);           // N*128 fp16
    short* pWd  = (short*)(agg + (size_t)N * H);
    short* pW1s = pWd + 6 * 32768;
    short* pW2s = pW1s + 6 * 16384;
    float* Mb   = (float*)(pW2s + 6 * 16384);

    float* outL = (float*)d_out;
    float* outP = outL + (size_t)N * H;

    // occupancy-derived grid caps
    int bpcE = 0, bpcN = 0;
    if (hipOccupancyMaxActiveBlocksPerMultiprocessor(&bpcE, edge_mfma_kernel, 512, 0)
        != hipSuccess || bpcE < 1) bpcE = 2;
    if (hipOccupancyMaxActiveBlocksPerMultiprocessor(&bpcN, node_mfma_kernel, 256, 0)
        != hipSuccess || bpcN < 1) bpcN = 2;
    const int capE = bpcE * 256;
    const int capN = bpcN * 256;

    tobf16_kernel<<<512, 256, 0, stream>>>(x_lig, x_pock, A, Bb, N * H / 4);
    pack_kernel<<<256, 256, 0, stream>>>(Wd, W1, W2, W0, We, pWd, pW1s, pW2s, Mb);

    const double start_d = exp(-5.0);
    const float rs    = (float)start_d;
    const float rstep = (float)((1.0 - start_d) / 127.0);
    const float rbeta = (float)std::pow(2.0 / 128.0 * (1.0 - start_d), -2.0);

    auto conv = [&](const unsigned short* src,
                    const float* xdf, const unsigned short* xdb,
                    const int* ei_, const float* ew_, const float* ea_, int E,
                    int l, int tt, float* outf, unsigned short* outb,
                    int accum, int relu) {
        hipMemsetAsync(agg, 0, (size_t)N * H * sizeof(__half), stream);
        const int lt = l * 3 + tt;
        const int ntE = (E + 63) / 64;
        const int gE = ntE < capE ? ntE : capE;
        edge_mfma_kernel<<<gE, 512, 0, stream>>>(
            src, ei_, ew_, ea_,
            pWd + (size_t)lt * 32768, bd + (size_t)lt * 256,
            Mb + (size_t)lt * 512, be + (size_t)lt * 128,
            (__half2*)agg, E, ntE, rs, rstep, rbeta);
        const int ntN = (N + 63) / 64;
        const int gN = ntN < capN ? ntN : capN;
        node_mfma_kernel<<<gN, 256, 0, stream>>>(
            (const __half2*)agg, xdf, xdb,
            pW1s + (size_t)lt * 16384, b1 + (size_t)lt * 128,
            pW2s + (size_t)lt * 16384, b2 + (size_t)lt * 128,
            outf, outb, N, ntN, accum, relu);
    };

    // layer 0 (order matters: A is overwritten by bond0's node after lp0+bond0 edges read it)
    conv(A,  x_pock, nullptr, ei_lp,   ew_lp,   ea_lp,   E_lp,   0, 1, nullptr, C, 0, 1);
    conv(A,  x_lig,  nullptr, ei_bond, ew_bond, ea_bond, E_bond, 0, 0, nullptr, A, 0, 0);
    conv(Bb, x_lig,  nullptr, ei_pl,   ew_pl,   ea_pl,   E_pl,   0, 2, nullptr, A, 1, 1);
    // layer 1: lig_bf = A, pock_bf = C
    conv(A, nullptr, A, ei_bond, ew_bond, ea_bond, E_bond, 1, 0, outL, nullptr, 0, 0);
    conv(C, nullptr, A, ei_pl,   ew_pl,   ea_pl,   E_pl,   1, 2, outL, nullptr, 1, 0);
    conv(A, nullptr, C, ei_lp,   ew_lp,   ea_lp,   E_lp,   1, 1, outP, nullptr, 0, 0);
}

// Round 8
// 942.201 us; speedup vs baseline: 3.2554x; 3.2554x over previous
//
#include <hip/hip_runtime.h>
#include <hip/hip_bf16.h>
#include <hip/hip_fp16.h>
#include <cmath>

typedef __attribute__((ext_vector_type(8))) short short8_t;
typedef __attribute__((ext_vector_type(4))) float f32x4;

static __device__ __forceinline__ short f2bs(float f) {
    union { __hip_bfloat16 h; short s; } u;
    u.h = __float2bfloat16(f);
    return u.s;
}
static __device__ __forceinline__ float bs2f(unsigned int us) {
    union { float f; unsigned int i; } u;
    u.i = us << 16;
    return u.f;
}
static __device__ __forceinline__ unsigned int pack2bf(float a, float b) {
    return (unsigned int)(unsigned short)f2bs(a) |
           ((unsigned int)(unsigned short)f2bs(b) << 16);
}
// Barrier that waits only on LDS ops (lgkmcnt), NOT vmem: atomics/gathers keep
// flowing across it. All inter-wave deps in these kernels are LDS-only.
static __device__ __forceinline__ void lds_barrier() {
    asm volatile("s_waitcnt lgkmcnt(0)\n\ts_barrier" ::: "memory");
}

// ---------------------------------------------------------------------------
// Pack kernel: Wd/W1/W2 -> bf16 MFMA B-fragment order; M = W0t @ We (fp32).
// ---------------------------------------------------------------------------
__global__ void pack_kernel(const float* __restrict__ Wd,
                            const float* __restrict__ W1,
                            const float* __restrict__ W2,
                            const float* __restrict__ W0,
                            const float* __restrict__ We,
                            short* __restrict__ pWd,
                            short* __restrict__ pW1,
                            short* __restrict__ pW2,
                            float* __restrict__ Mb)
{
    const int tid = blockIdx.x * blockDim.x + threadIdx.x;
    const int stride = gridDim.x * blockDim.x;
    for (int i = tid; i < 6 * 32768; i += stride) {
        int c = i >> 15, rem = i & 32767;
        int f = rem >> 9, l = (rem >> 3) & 63, j = rem & 7;
        int kk = f >> 4, nt = f & 15;
        int k = kk * 32 + (l >> 4) * 8 + j;
        int n = nt * 16 + (l & 15);
        pWd[i] = f2bs(Wd[(size_t)c * 32768 + k * 256 + n]);
    }
    for (int i = tid; i < 6 * 16384; i += stride) {
        int c = i >> 14, rem = i & 16383;
        int f = rem >> 9, l = (rem >> 3) & 63, j = rem & 7;
        int kk = f >> 3, nt = f & 7;
        int k = kk * 32 + (l >> 4) * 8 + j;
        int n = nt * 16 + (l & 15);
        pW1[i] = f2bs(W1[(size_t)c * 16384 + k * 128 + n]);
        pW2[i] = f2bs(W2[(size_t)c * 16384 + k * 128 + n]);
    }
    for (int i = tid; i < 6 * 512; i += stride) {
        int c = i >> 9, rem = i & 511;
        int a = rem >> 7, h = rem & 127;
        int t = c % 3;
        float m = 0.f;
        #pragma unroll
        for (int j = 0; j < 4; ++j)
            m = fmaf(W0[t * 16 + a * 4 + j], We[(size_t)c * 512 + j * 128 + h], m);
        Mb[i] = m;
    }
}

// ---------------------------------------------------------------------------
// Convert fp32 -> bf16 (two arrays)
// ---------------------------------------------------------------------------
__global__ void tobf16_kernel(const float* __restrict__ a, const float* __restrict__ b,
                              unsigned short* __restrict__ oa, unsigned short* __restrict__ ob,
                              int n4)
{
    int i = blockIdx.x * blockDim.x + threadIdx.x;
    const int stride = gridDim.x * blockDim.x;
    for (; i < n4; i += stride) {
        float4 va = ((const float4*)a)[i];
        uint2 pa; pa.x = pack2bf(va.x, va.y); pa.y = pack2bf(va.z, va.w);
        ((uint2*)oa)[i] = pa;
        float4 vb = ((const float4*)b)[i];
        uint2 pb; pb.x = pack2bf(vb.x, vb.y); pb.y = pack2bf(vb.z, vb.w);
        ((uint2*)ob)[i] = pb;
    }
}

// ---------------------------------------------------------------------------
// Edge kernel (persistent, 512 threads / 8 waves, 64 edges/tile).
// Wave w owns output cols [32w, 32w+32) (nt = 2w, 2w+1) AND flush rows
// [8w, 8w+8) — so xj stays in registers (no sXj LDS).
// Phase A: rbf (k-slice [16w,16w+16)) -> sRbf; xj -> regs.      bar1
// Phase B: next-tile meta prefetch; GEMM; acc+bd -> sSS (fp16);
//          next-tile gathers.                                   bar2
// Phase C: msg = relu(xj*scale+shift) from sSS; fp16x2 atomics (issued last).
// LDS 48KB: sRbf 16KB + sSS 32KB.
// __launch_bounds__(512, 2): empirically VGPR cap = 512/(2*w) = 128 — the
// 4-waves/SIMD occupancy step. (R4/R7 lesson: w=3/w=4 -> caps 84/64 -> spills.)
// ---------------------------------------------------------------------------
__global__ __launch_bounds__(512, 2)
void edge_mfma_kernel(
    const unsigned short* __restrict__ xsb,   // bf16 x_src (N,128)
    const int* __restrict__ ei,
    const float* __restrict__ ew, const float* __restrict__ ea,
    const short* __restrict__ pWd, const float* __restrict__ bd,
    const float* __restrict__ Mb, const float* __restrict__ be,
    __half2* __restrict__ agg, int E, int ntiles,
    float rs, float rstep, float rbeta)
{
    __shared__ short sRbf[64 * 128];   // bf16, swizzled [edge][k], 16KB
    __shared__ __half sSS[64 * 256];   // fp16, swizzled [edge][col], 32KB

    const int t = threadIdx.x;
    const int lane = t & 63;
    const int w = t >> 6;          // 0..7
    const int l15 = lane & 15;
    const int l4 = lane >> 4;

    // --- per-block constants ---
    short8_t bfrag[4][2];          // [kk][i], nt = 2w+i
    #pragma unroll
    for (int kk = 0; kk < 4; ++kk)
        #pragma unroll
        for (int i = 0; i < 2; ++i)
            bfrag[kk][i] = *(const short8_t*)&pWd[((kk * 16 + 2 * w + i) * 64 + lane) * 8];
    float bdv[2];
    #pragma unroll
    for (int i = 0; i < 2; ++i) bdv[i] = bd[(2 * w + i) * 16 + l15];
    const float be0 = be[2 * lane], be1 = be[2 * lane + 1];
    float ma0[4], ma1[4];
    #pragma unroll
    for (int a = 0; a < 4; ++a) {
        ma0[a] = Mb[a * 128 + 2 * lane];
        ma1[a] = Mb[a * 128 + 2 * lane + 1];
    }

    const int stride = gridDim.x;
    int tile = blockIdx.x;
    if (tile >= ntiles) return;

    // ---- prologue: meta + gathers for first tile ----
    float dd_c; int dst_c; float4 ea_c;
    unsigned int gx[8];
    {
        const int e0 = tile << 6;
        int eL = e0 + lane;
        int eLc = eL < E ? eL : E - 1;
        dd_c = ew[eLc];
        int es = e0 + w * 8 + (lane & 7);
        int esv = es < E ? es : E - 1;
        dst_c = (es < E) ? ei[E + esv] : -1;
        int src_c = ei[esv];
        ea_c = *(const float4*)&ea[(size_t)esv * 4];
        #pragma unroll
        for (int r = 0; r < 8; ++r) {
            int srn = __shfl(src_c, r);
            gx[r] = *(const unsigned int*)&xsb[(size_t)srn * 128 + lane * 2];
        }
    }

    for (; tile < ntiles; tile += stride) {
        // ---- phase A: rbf -> sRbf (k-slice), xj -> regs ----
        const float edv = __expf(-dd_c);
        const float dcc = fminf(dd_c, 5.0f);
        const float cutv = 0.5f * (__cosf(dcc * 0.62831853071795864769f) + 1.0f);
        {
            char* base = (char*)sRbf + lane * 256;
            #pragma unroll
            for (int c = 0; c < 2; ++c) {
                short8_t v;
                #pragma unroll
                for (int j = 0; j < 8; ++j) {
                    float mean = rs + (float)(w * 16 + c * 8 + j) * rstep;
                    float diff = edv - mean;
                    v[j] = f2bs(cutv * __expf(-rbeta * diff * diff));
                }
                *(short8_t*)(base + ((w * 32 + c * 16) ^ ((lane & 7) << 4))) = v;
            }
        }
        unsigned int xjr[8];
        #pragma unroll
        for (int r = 0; r < 8; ++r) {
            float ea0 = __shfl(ea_c.x, r), ea1 = __shfl(ea_c.y, r);
            float ea2 = __shfl(ea_c.z, r), ea3 = __shfl(ea_c.w, r);
            unsigned int g = gx[r];
            float x0 = bs2f(g & 0xffffu), x1 = bs2f(g >> 16);
            float o0 = x0 + be0 + ea0 * ma0[0] + ea1 * ma0[1] + ea2 * ma0[2] + ea3 * ma0[3];
            float o1 = x1 + be1 + ea0 * ma1[0] + ea1 * ma1[1] + ea2 * ma1[2] + ea3 * ma1[3];
            xjr[r] = pack2bf(o0, o1);
        }

        lds_barrier();   // bar1: sRbf visible (also fences prev-tile sSS reads)

        // ---- phase B ----
        const int ntile = tile + stride;
        const bool has_next = ntile < ntiles;
        float dd_n = 0.f; int dst_n = -1; int src_n = 0;
        float4 ea_n = {0.f, 0.f, 0.f, 0.f};
        if (has_next) {   // issue next-tile meta loads before any atomics
            const int e0n = ntile << 6;
            int eL = e0n + lane;
            int eLc = eL < E ? eL : E - 1;
            dd_n = ew[eLc];
            int es = e0n + w * 8 + (lane & 7);
            int esv = es < E ? es : E - 1;
            dst_n = (es < E) ? ei[E + esv] : -1;
            src_n = ei[esv];
            ea_n = *(const float4*)&ea[(size_t)esv * 4];
        }
        __builtin_amdgcn_sched_barrier(0);   // pin prefetch issue before GEMM

        // GEMM: ss(64 x 32cols/wave) = rbf(64x128) @ Wd-slice
        f32x4 acc[4][2];
        #pragma unroll
        for (int m = 0; m < 4; ++m) {
            acc[m][0] = (f32x4){0.f, 0.f, 0.f, 0.f};
            acc[m][1] = (f32x4){0.f, 0.f, 0.f, 0.f};
        }
        #pragma unroll
        for (int kk = 0; kk < 4; ++kk) {
            short8_t af[4];
            #pragma unroll
            for (int m = 0; m < 4; ++m) {
                int row = m * 16 + l15;
                int byte = row * 256 + ((kk * 64 + l4 * 16) ^ ((row & 7) << 4));
                af[m] = *(const short8_t*)((const char*)sRbf + byte);
            }
            #pragma unroll
            for (int m = 0; m < 4; ++m)
                #pragma unroll
                for (int i = 0; i < 2; ++i)
                    acc[m][i] = __builtin_amdgcn_mfma_f32_16x16x32_bf16(
                        af[m], bfrag[kk][i], acc[m][i], 0, 0, 0);
        }

        // ss = acc + bd -> sSS fp16 (swizzled [edge][col])
        #pragma unroll
        for (int m = 0; m < 4; ++m)
            #pragma unroll
            for (int i = 0; i < 2; ++i) {
                int col = (2 * w + i) * 16 + l15;
                #pragma unroll
                for (int r = 0; r < 4; ++r) {
                    int row = m * 16 + l4 * 4 + r;
                    int byte = row * 512 + ((col * 2) ^ ((row & 7) << 4));
                    *(__half*)((char*)sSS + byte) = __float2half(acc[m][i][r] + bdv[i]);
                }
            }

        // issue next-tile gathers (acc dead; still before atomics)
        if (has_next) {
            #pragma unroll
            for (int r = 0; r < 8; ++r) {
                int srn = __shfl(src_n, r);
                gx[r] = *(const unsigned int*)&xsb[(size_t)srn * 128 + lane * 2];
            }
        }
        const int dst_f = dst_c;
        dd_c = dd_n; dst_c = dst_n; ea_c = ea_n;

        lds_barrier();   // bar2: sSS visible; sRbf GEMM reads done

        // ---- phase C: msg + fp16x2 atomics (own rows [8w,8w+8)) ----
        #pragma unroll
        for (int r = 0; r < 8; ++r) {
            int e = 8 * w + r;
            int dst = __shfl(dst_f, r);
            unsigned int sc = *(const unsigned int*)
                ((const char*)sSS + e * 512 + ((lane * 4) ^ ((e & 7) << 4)));
            unsigned int sh = *(const unsigned int*)
                ((const char*)sSS + e * 512 + ((256 + lane * 4) ^ ((e & 7) << 4)));
            float2 scf = __half22float2(*(const __half2*)&sc);
            float2 shf = __half22float2(*(const __half2*)&sh);
            unsigned int g = xjr[r];
            float x0 = bs2f(g & 0xffffu), x1 = bs2f(g >> 16);
            float m0 = fmaxf(fmaf(x0, scf.x, shf.x), 0.0f);
            float m1 = fmaxf(fmaf(x1, scf.y, shf.y), 0.0f);
            __half2 hv = __floats2half2_rn(m0, m1);
            unsigned int hbits = *(unsigned int*)&hv;
            // skip exact-zero messages (agg only holds {+0, positive})
            if (dst >= 0 && hbits != 0u)
                unsafeAtomicAdd(agg + (size_t)dst * 64 + lane, hv);
        }
    }
}

// ---------------------------------------------------------------------------
// Node kernel (persistent): out = relu((agg+x)@W1+b1)@W2+b2 (+prev, relu opt)
// agg fp16; x_dst fp32 OR bf16; out fp32 OR bf16. 2 lgkm-barriers per tile.
// ---------------------------------------------------------------------------
__global__ __launch_bounds__(256)
void node_mfma_kernel(
    const __half2* __restrict__ agg,
    const float* __restrict__ xdf, const unsigned short* __restrict__ xdb,
    const short* __restrict__ pW1, const float* __restrict__ b1,
    const short* __restrict__ pW2, const float* __restrict__ b2,
    float* __restrict__ outf, unsigned short* __restrict__ outb,
    int N, int ntiles, int accumulate, int relu_out)
{
    __shared__ short sA[64 * 128];
    __shared__ short sH[64 * 128];

    const int t = threadIdx.x;
    const int lane = t & 63;
    const int w = t >> 6;
    const int l15 = lane & 15;
    const int l4 = lane >> 4;

    short8_t w1f[4][2], w2f[4][2];
    #pragma unroll
    for (int kk = 0; kk < 4; ++kk)
        #pragma unroll
        for (int p = 0; p < 2; ++p) {
            int nt = 2 * w + p;
            w1f[kk][p] = *(const short8_t*)&pW1[((kk * 8 + nt) * 64 + lane) * 8];
            w2f[kk][p] = *(const short8_t*)&pW2[((kk * 8 + nt) * 64 + lane) * 8];
        }
    float b1v[2], b2v[2];
    #pragma unroll
    for (int p = 0; p < 2; ++p) {
        int col = (2 * w + p) * 16 + l15;
        b1v[p] = b1[col];
        b2v[p] = b2[col];
    }

    for (int tile = blockIdx.x; tile < ntiles; tile += gridDim.x) {
        const int n0 = tile << 6;
        // --- stage A = bf16(fp16 agg + x_dst) ---
        #pragma unroll
        for (int i = 0; i < 4; ++i) {
            int idx = i * 256 + t;          // 64 rows x 16 chunks of 8 cols
            int row = idx >> 4, c8 = idx & 15;
            int gr = n0 + row; if (gr >= N) gr = N - 1;
            union { float4 f; __half2 h[4]; } ar;
            ar.f = ((const float4*)agg)[(size_t)gr * 16 + c8];
            float xv[8];
            if (xdf) {
                float4 x0 = ((const float4*)xdf)[(size_t)gr * 32 + c8 * 2];
                float4 x1 = ((const float4*)xdf)[(size_t)gr * 32 + c8 * 2 + 1];
                xv[0] = x0.x; xv[1] = x0.y; xv[2] = x0.z; xv[3] = x0.w;
                xv[4] = x1.x; xv[5] = x1.y; xv[6] = x1.z; xv[7] = x1.w;
            } else {
                uint4 xr = ((const uint4*)xdb)[(size_t)gr * 16 + c8];
                xv[0] = bs2f(xr.x & 0xffffu); xv[1] = bs2f(xr.x >> 16);
                xv[2] = bs2f(xr.y & 0xffffu); xv[3] = bs2f(xr.y >> 16);
                xv[4] = bs2f(xr.z & 0xffffu); xv[5] = bs2f(xr.z >> 16);
                xv[6] = bs2f(xr.w & 0xffffu); xv[7] = bs2f(xr.w >> 16);
            }
            short8_t v;
            #pragma unroll
            for (int j = 0; j < 4; ++j) {
                float2 a2 = __half22float2(ar.h[j]);
                v[2 * j]     = f2bs(a2.x + xv[2 * j]);
                v[2 * j + 1] = f2bs(a2.y + xv[2 * j + 1]);
            }
            int byte = row * 256 + ((c8 * 16) ^ ((row & 7) << 4));
            *(short8_t*)((char*)sA + byte) = v;
        }
        lds_barrier();

        // --- GEMM1 ---
        f32x4 acc[4][2];
        #pragma unroll
        for (int m = 0; m < 4; ++m) {
            acc[m][0] = (f32x4){0.f, 0.f, 0.f, 0.f};
            acc[m][1] = (f32x4){0.f, 0.f, 0.f, 0.f};
        }
        #pragma unroll
        for (int kk = 0; kk < 4; ++kk) {
            short8_t af[4];
            #pragma unroll
            for (int m = 0; m < 4; ++m) {
                int row = m * 16 + l15;
                int byte = row * 256 + ((kk * 64 + l4 * 16) ^ ((row & 7) << 4));
                af[m] = *(const short8_t*)((const char*)sA + byte);
            }
            #pragma unroll
            for (int m = 0; m < 4; ++m)
                #pragma unroll
                for (int p = 0; p < 2; ++p)
                    acc[m][p] = __builtin_amdgcn_mfma_f32_16x16x32_bf16(
                        af[m], w1f[kk][p], acc[m][p], 0, 0, 0);
        }
        #pragma unroll
        for (int m = 0; m < 4; ++m)
            #pragma unroll
            for (int p = 0; p < 2; ++p) {
                int col = (2 * w + p) * 16 + l15;
                #pragma unroll
                for (int r = 0; r < 4; ++r) {
                    int row = m * 16 + l4 * 4 + r;
                    short hs = f2bs(fmaxf(acc[m][p][r] + b1v[p], 0.f));
                    int byte = row * 256 + ((col * 2) ^ ((row & 7) << 4));
                    *(short*)((char*)sH + byte) = hs;
                }
            }
        lds_barrier();

        // --- GEMM2 ---
        f32x4 acc2[4][2];
        #pragma unroll
        for (int m = 0; m < 4; ++m) {
            acc2[m][0] = (f32x4){0.f, 0.f, 0.f, 0.f};
            acc2[m][1] = (f32x4){0.f, 0.f, 0.f, 0.f};
        }
        #pragma unroll
        for (int kk = 0; kk < 4; ++kk) {
            short8_t af[4];
            #pragma unroll
            for (int m = 0; m < 4; ++m) {
                int row = m * 16 + l15;
                int byte = row * 256 + ((kk * 64 + l4 * 16) ^ ((row & 7) << 4));
                af[m] = *(const short8_t*)((const char*)sH + byte);
            }
            #pragma unroll
            for (int m = 0; m < 4; ++m)
                #pragma unroll
                for (int p = 0; p < 2; ++p)
                    acc2[m][p] = __builtin_amdgcn_mfma_f32_16x16x32_bf16(
                        af[m], w2f[kk][p], acc2[m][p], 0, 0, 0);
        }
        // --- epilogue ---
        #pragma unroll
        for (int m = 0; m < 4; ++m)
            #pragma unroll
            for (int p = 0; p < 2; ++p) {
                int col = (2 * w + p) * 16 + l15;
                #pragma unroll
                for (int r = 0; r < 4; ++r) {
                    int row = n0 + m * 16 + l4 * 4 + r;
                    if (row < N) {
                        float v = acc2[m][p][r] + b2v[p];
                        if (outf) {
                            float* op = &outf[(size_t)row * 128 + col];
                            if (accumulate) v += *op;
                            if (relu_out) v = fmaxf(v, 0.f);
                            *op = v;
                        } else {
                            unsigned short* op = &outb[(size_t)row * 128 + col];
                            if (accumulate) v += bs2f((unsigned int)*op);
                            if (relu_out) v = fmaxf(v, 0.f);
                            *op = (unsigned short)f2bs(v);
                        }
                    }
                }
            }
    }
}

// ---------------------------------------------------------------------------
extern "C" void kernel_launch(void* const* d_in, const int* in_sizes, int n_in,
                              void* d_out, int out_size, void* d_ws, size_t ws_size,
                              hipStream_t stream)
{
    const float* x_lig   = (const float*)d_in[0];
    const float* x_pock  = (const float*)d_in[1];
    const int*   ei_bond = (const int*)d_in[2];
    const float* ew_bond = (const float*)d_in[3];
    const float* ea_bond = (const float*)d_in[4];
    const int*   ei_lp   = (const int*)d_in[5];
    const float* ew_lp   = (const float*)d_in[6];
    const float* ea_lp   = (const float*)d_in[7];
    const int*   ei_pl   = (const int*)d_in[8];
    const float* ew_pl   = (const float*)d_in[9];
    const float* ea_pl   = (const float*)d_in[10];
    const float* W0 = (const float*)d_in[11];
    const float* Wd = (const float*)d_in[12];
    const float* bd = (const float*)d_in[13];
    const float* We = (const float*)d_in[14];
    const float* be = (const float*)d_in[15];
    const float* W1 = (const float*)d_in[16];
    const float* b1 = (const float*)d_in[17];
    const float* W2 = (const float*)d_in[18];
    const float* b2 = (const float*)d_in[19];

    const int H = 128;
    const int N = in_sizes[0] / H;
    const int E_bond = in_sizes[3];
    const int E_lp   = in_sizes[6];
    const int E_pl   = in_sizes[9];

    // workspace: A,B,C bf16 activations; agg fp16; packed weights
    unsigned short* A  = (unsigned short*)d_ws;           // x_lig_bf -> lig0_bf
    unsigned short* Bb = A  + (size_t)N * H;              // x_pock_bf
    unsigned short* C  = Bb + (size_t)N * H;              // pock0_bf
    __half* agg = (__half*)(C + (size_t)N * H);           // N*128 fp16
    short* pWd  = (short*)(agg + (size_t)N * H);
    short* pW1s = pWd + 6 * 32768;
    short* pW2s = pW1s + 6 * 16384;
    float* Mb   = (float*)(pW2s + 6 * 16384);

    float* outL = (float*)d_out;
    float* outP = outL + (size_t)N * H;

    // occupancy-derived grid caps
    int bpcE = 0, bpcN = 0;
    if (hipOccupancyMaxActiveBlocksPerMultiprocessor(&bpcE, edge_mfma_kernel, 512, 0)
        != hipSuccess || bpcE < 1) bpcE = 2;
    if (hipOccupancyMaxActiveBlocksPerMultiprocessor(&bpcN, node_mfma_kernel, 256, 0)
        != hipSuccess || bpcN < 1) bpcN = 2;
    const int capE = bpcE * 256;
    const int capN = bpcN * 256;

    tobf16_kernel<<<512, 256, 0, stream>>>(x_lig, x_pock, A, Bb, N * H / 4);
    pack_kernel<<<256, 256, 0, stream>>>(Wd, W1, W2, W0, We, pWd, pW1s, pW2s, Mb);

    const double start_d = exp(-5.0);
    const float rs    = (float)start_d;
    const float rstep = (float)((1.0 - start_d) / 127.0);
    const float rbeta = (float)std::pow(2.0 / 128.0 * (1.0 - start_d), -2.0);

    auto conv = [&](const unsigned short* src,
                    const float* xdf, const unsigned short* xdb,
                    const int* ei_, const float* ew_, const float* ea_, int E,
                    int l, int tt, float* outf, unsigned short* outb,
                    int accum, int relu) {
        hipMemsetAsync(agg, 0, (size_t)N * H * sizeof(__half), stream);
        const int lt = l * 3 + tt;
        const int ntE = (E + 63) / 64;
        const int gE = ntE < capE ? ntE : capE;
        edge_mfma_kernel<<<gE, 512, 0, stream>>>(
            src, ei_, ew_, ea_,
            pWd + (size_t)lt * 32768, bd + (size_t)lt * 256,
            Mb + (size_t)lt * 512, be + (size_t)lt * 128,
            (__half2*)agg, E, ntE, rs, rstep, rbeta);
        const int ntN = (N + 63) / 64;
        const int gN = ntN < capN ? ntN : capN;
        node_mfma_kernel<<<gN, 256, 0, stream>>>(
            (const __half2*)agg, xdf, xdb,
            pW1s + (size_t)lt * 16384, b1 + (size_t)lt * 128,
            pW2s + (size_t)lt * 16384, b2 + (size_t)lt * 128,
            outf, outb, N, ntN, accum, relu);
    };

    // layer 0 (order matters: A is overwritten by bond0's node after lp0+bond0 edges read it)
    conv(A,  x_pock, nullptr, ei_lp,   ew_lp,   ea_lp,   E_lp,   0, 1, nullptr, C, 0, 1);
    conv(A,  x_lig,  nullptr, ei_bond, ew_bond, ea_bond, E_bond, 0, 0, nullptr, A, 0, 0);
    conv(Bb, x_lig,  nullptr, ei_pl,   ew_pl,   ea_pl,   E_pl,   0, 2, nullptr, A, 1, 1);
    // layer 1: lig_bf = A, pock_bf = C
    conv(A, nullptr, A, ei_bond, ew_bond, ea_bond, E_bond, 1, 0, outL, nullptr, 0, 0);
    conv(C, nullptr, A, ei_pl,   ew_pl,   ea_pl,   E_pl,   1, 2, outL, nullptr, 1, 0);
    conv(A, nullptr, C, ei_lp,   ew_lp,   ea_lp,   E_lp,   1, 1, outP, nullptr, 0, 0);
}

// Round 9
// 851.812 us; speedup vs baseline: 3.6009x; 1.1061x over previous
//
#include <hip/hip_runtime.h>
#include <hip/hip_bf16.h>
#include <hip/hip_fp16.h>
#include <cmath>

typedef __attribute__((ext_vector_type(8))) short short8_t;
typedef __attribute__((ext_vector_type(4))) float f32x4;

static __device__ __forceinline__ short f2bs(float f) {
    union { __hip_bfloat16 h; short s; } u;
    u.h = __float2bfloat16(f);
    return u.s;
}
static __device__ __forceinline__ float bs2f(unsigned int us) {
    union { float f; unsigned int i; } u;
    u.i = us << 16;
    return u.f;
}
static __device__ __forceinline__ unsigned int pack2bf(float a, float b) {
    return (unsigned int)(unsigned short)f2bs(a) |
           ((unsigned int)(unsigned short)f2bs(b) << 16);
}
// Barrier that waits only on LDS ops (lgkmcnt), NOT vmem: atomics/gathers keep
// flowing across it. All inter-wave deps in these kernels are LDS-only.
static __device__ __forceinline__ void lds_barrier() {
    asm volatile("s_waitcnt lgkmcnt(0)\n\ts_barrier" ::: "memory");
}

// ---------------------------------------------------------------------------
// Pack kernel: Wd/W1/W2 -> bf16 MFMA B-fragment order; M = W0t @ We (fp32).
// ---------------------------------------------------------------------------
__global__ void pack_kernel(const float* __restrict__ Wd,
                            const float* __restrict__ W1,
                            const float* __restrict__ W2,
                            const float* __restrict__ W0,
                            const float* __restrict__ We,
                            short* __restrict__ pWd,
                            short* __restrict__ pW1,
                            short* __restrict__ pW2,
                            float* __restrict__ Mb)
{
    const int tid = blockIdx.x * blockDim.x + threadIdx.x;
    const int stride = gridDim.x * blockDim.x;
    for (int i = tid; i < 6 * 32768; i += stride) {
        int c = i >> 15, rem = i & 32767;
        int f = rem >> 9, l = (rem >> 3) & 63, j = rem & 7;
        int kk = f >> 4, nt = f & 15;
        int k = kk * 32 + (l >> 4) * 8 + j;
        int n = nt * 16 + (l & 15);
        pWd[i] = f2bs(Wd[(size_t)c * 32768 + k * 256 + n]);
    }
    for (int i = tid; i < 6 * 16384; i += stride) {
        int c = i >> 14, rem = i & 16383;
        int f = rem >> 9, l = (rem >> 3) & 63, j = rem & 7;
        int kk = f >> 3, nt = f & 7;
        int k = kk * 32 + (l >> 4) * 8 + j;
        int n = nt * 16 + (l & 15);
        pW1[i] = f2bs(W1[(size_t)c * 16384 + k * 128 + n]);
        pW2[i] = f2bs(W2[(size_t)c * 16384 + k * 128 + n]);
    }
    for (int i = tid; i < 6 * 512; i += stride) {
        int c = i >> 9, rem = i & 511;
        int a = rem >> 7, h = rem & 127;
        int t = c % 3;
        float m = 0.f;
        #pragma unroll
        for (int j = 0; j < 4; ++j)
            m = fmaf(W0[t * 16 + a * 4 + j], We[(size_t)c * 512 + j * 128 + h], m);
        Mb[i] = m;
    }
}

// ---------------------------------------------------------------------------
// Convert fp32 -> bf16 (two arrays)
// ---------------------------------------------------------------------------
__global__ void tobf16_kernel(const float* __restrict__ a, const float* __restrict__ b,
                              unsigned short* __restrict__ oa, unsigned short* __restrict__ ob,
                              int n4)
{
    int i = blockIdx.x * blockDim.x + threadIdx.x;
    const int stride = gridDim.x * blockDim.x;
    for (; i < n4; i += stride) {
        float4 va = ((const float4*)a)[i];
        uint2 pa; pa.x = pack2bf(va.x, va.y); pa.y = pack2bf(va.z, va.w);
        ((uint2*)oa)[i] = pa;
        float4 vb = ((const float4*)b)[i];
        uint2 pb; pb.x = pack2bf(vb.x, vb.y); pb.y = pack2bf(vb.z, vb.w);
        ((uint2*)ob)[i] = pb;
    }
}

// ---------------------------------------------------------------------------
// Edge kernel (persistent, 512 threads / 8 waves, 64 edges/tile).
// Wave w owns output cols [32w, 32w+32) (nt = 2w, 2w+1) AND flush rows
// [8w, 8w+8) — so xj stays in registers (no sXj LDS).
// Phase A: rbf (k-slice [16w,16w+16)) -> sRbf; xj -> regs.      bar1
// Phase B: next-tile meta prefetch; GEMM; acc+bd -> sSS (fp16);
//          next-tile gathers.                                   bar2
// Phase C: msg = relu(xj*scale+shift) from sSS; fp16x2 atomics (issued last).
// LDS 48KB: sRbf 16KB + sSS 32KB.
// __launch_bounds__(512, 2): VGPR cap 128 = 4 waves/SIMD step (R8: VGPR 124,
// no spills). Grid is set EXPLICITLY to 2 blocks/CU — the occupancy API
// under-reports (uses 64KB shared-mem budget, returns 1 block/CU; R6/R8
// measured occupancy matched 1 block/CU exactly).
// ---------------------------------------------------------------------------
__global__ __launch_bounds__(512, 2)
void edge_mfma_kernel(
    const unsigned short* __restrict__ xsb,   // bf16 x_src (N,128)
    const int* __restrict__ ei,
    const float* __restrict__ ew, const float* __restrict__ ea,
    const short* __restrict__ pWd, const float* __restrict__ bd,
    const float* __restrict__ Mb, const float* __restrict__ be,
    __half2* __restrict__ agg, int E, int ntiles,
    float rs, float rstep, float rbeta)
{
    __shared__ short sRbf[64 * 128];   // bf16, swizzled [edge][k], 16KB
    __shared__ __half sSS[64 * 256];   // fp16, swizzled [edge][col], 32KB

    const int t = threadIdx.x;
    const int lane = t & 63;
    const int w = t >> 6;          // 0..7
    const int l15 = lane & 15;
    const int l4 = lane >> 4;

    // --- per-block constants ---
    short8_t bfrag[4][2];          // [kk][i], nt = 2w+i
    #pragma unroll
    for (int kk = 0; kk < 4; ++kk)
        #pragma unroll
        for (int i = 0; i < 2; ++i)
            bfrag[kk][i] = *(const short8_t*)&pWd[((kk * 16 + 2 * w + i) * 64 + lane) * 8];
    float bdv[2];
    #pragma unroll
    for (int i = 0; i < 2; ++i) bdv[i] = bd[(2 * w + i) * 16 + l15];
    const float be0 = be[2 * lane], be1 = be[2 * lane + 1];
    float ma0[4], ma1[4];
    #pragma unroll
    for (int a = 0; a < 4; ++a) {
        ma0[a] = Mb[a * 128 + 2 * lane];
        ma1[a] = Mb[a * 128 + 2 * lane + 1];
    }

    const int stride = gridDim.x;
    int tile = blockIdx.x;
    if (tile >= ntiles) return;

    // ---- prologue: meta + gathers for first tile ----
    float dd_c; int dst_c; float4 ea_c;
    unsigned int gx[8];
    {
        const int e0 = tile << 6;
        int eL = e0 + lane;
        int eLc = eL < E ? eL : E - 1;
        dd_c = ew[eLc];
        int es = e0 + w * 8 + (lane & 7);
        int esv = es < E ? es : E - 1;
        dst_c = (es < E) ? ei[E + esv] : -1;
        int src_c = ei[esv];
        ea_c = *(const float4*)&ea[(size_t)esv * 4];
        #pragma unroll
        for (int r = 0; r < 8; ++r) {
            int srn = __shfl(src_c, r);
            gx[r] = *(const unsigned int*)&xsb[(size_t)srn * 128 + lane * 2];
        }
    }

    for (; tile < ntiles; tile += stride) {
        // ---- phase A: rbf -> sRbf (k-slice), xj -> regs ----
        const float edv = __expf(-dd_c);
        const float dcc = fminf(dd_c, 5.0f);
        const float cutv = 0.5f * (__cosf(dcc * 0.62831853071795864769f) + 1.0f);
        {
            char* base = (char*)sRbf + lane * 256;
            #pragma unroll
            for (int c = 0; c < 2; ++c) {
                short8_t v;
                #pragma unroll
                for (int j = 0; j < 8; ++j) {
                    float mean = rs + (float)(w * 16 + c * 8 + j) * rstep;
                    float diff = edv - mean;
                    v[j] = f2bs(cutv * __expf(-rbeta * diff * diff));
                }
                *(short8_t*)(base + ((w * 32 + c * 16) ^ ((lane & 7) << 4))) = v;
            }
        }
        unsigned int xjr[8];
        #pragma unroll
        for (int r = 0; r < 8; ++r) {
            float ea0 = __shfl(ea_c.x, r), ea1 = __shfl(ea_c.y, r);
            float ea2 = __shfl(ea_c.z, r), ea3 = __shfl(ea_c.w, r);
            unsigned int g = gx[r];
            float x0 = bs2f(g & 0xffffu), x1 = bs2f(g >> 16);
            float o0 = x0 + be0 + ea0 * ma0[0] + ea1 * ma0[1] + ea2 * ma0[2] + ea3 * ma0[3];
            float o1 = x1 + be1 + ea0 * ma1[0] + ea1 * ma1[1] + ea2 * ma1[2] + ea3 * ma1[3];
            xjr[r] = pack2bf(o0, o1);
        }

        lds_barrier();   // bar1: sRbf visible (also fences prev-tile sSS reads)

        // ---- phase B ----
        const int ntile = tile + stride;
        const bool has_next = ntile < ntiles;
        float dd_n = 0.f; int dst_n = -1; int src_n = 0;
        float4 ea_n = {0.f, 0.f, 0.f, 0.f};
        if (has_next) {   // issue next-tile meta loads before any atomics
            const int e0n = ntile << 6;
            int eL = e0n + lane;
            int eLc = eL < E ? eL : E - 1;
            dd_n = ew[eLc];
            int es = e0n + w * 8 + (lane & 7);
            int esv = es < E ? es : E - 1;
            dst_n = (es < E) ? ei[E + esv] : -1;
            src_n = ei[esv];
            ea_n = *(const float4*)&ea[(size_t)esv * 4];
        }
        __builtin_amdgcn_sched_barrier(0);   // pin prefetch issue before GEMM

        // GEMM: ss(64 x 32cols/wave) = rbf(64x128) @ Wd-slice
        f32x4 acc[4][2];
        #pragma unroll
        for (int m = 0; m < 4; ++m) {
            acc[m][0] = (f32x4){0.f, 0.f, 0.f, 0.f};
            acc[m][1] = (f32x4){0.f, 0.f, 0.f, 0.f};
        }
        #pragma unroll
        for (int kk = 0; kk < 4; ++kk) {
            short8_t af[4];
            #pragma unroll
            for (int m = 0; m < 4; ++m) {
                int row = m * 16 + l15;
                int byte = row * 256 + ((kk * 64 + l4 * 16) ^ ((row & 7) << 4));
                af[m] = *(const short8_t*)((const char*)sRbf + byte);
            }
            #pragma unroll
            for (int m = 0; m < 4; ++m)
                #pragma unroll
                for (int i = 0; i < 2; ++i)
                    acc[m][i] = __builtin_amdgcn_mfma_f32_16x16x32_bf16(
                        af[m], bfrag[kk][i], acc[m][i], 0, 0, 0);
        }

        // ss = acc + bd -> sSS fp16 (swizzled [edge][col])
        #pragma unroll
        for (int m = 0; m < 4; ++m)
            #pragma unroll
            for (int i = 0; i < 2; ++i) {
                int col = (2 * w + i) * 16 + l15;
                #pragma unroll
                for (int r = 0; r < 4; ++r) {
                    int row = m * 16 + l4 * 4 + r;
                    int byte = row * 512 + ((col * 2) ^ ((row & 7) << 4));
                    *(__half*)((char*)sSS + byte) = __float2half(acc[m][i][r] + bdv[i]);
                }
            }

        // issue next-tile gathers (acc dead; still before atomics)
        if (has_next) {
            #pragma unroll
            for (int r = 0; r < 8; ++r) {
                int srn = __shfl(src_n, r);
                gx[r] = *(const unsigned int*)&xsb[(size_t)srn * 128 + lane * 2];
            }
        }
        const int dst_f = dst_c;
        dd_c = dd_n; dst_c = dst_n; ea_c = ea_n;

        lds_barrier();   // bar2: sSS visible; sRbf GEMM reads done

        // ---- phase C: msg + fp16x2 atomics (own rows [8w,8w+8)) ----
        #pragma unroll
        for (int r = 0; r < 8; ++r) {
            int e = 8 * w + r;
            int dst = __shfl(dst_f, r);
            unsigned int sc = *(const unsigned int*)
                ((const char*)sSS + e * 512 + ((lane * 4) ^ ((e & 7) << 4)));
            unsigned int sh = *(const unsigned int*)
                ((const char*)sSS + e * 512 + ((256 + lane * 4) ^ ((e & 7) << 4)));
            float2 scf = __half22float2(*(const __half2*)&sc);
            float2 shf = __half22float2(*(const __half2*)&sh);
            unsigned int g = xjr[r];
            float x0 = bs2f(g & 0xffffu), x1 = bs2f(g >> 16);
            float m0 = fmaxf(fmaf(x0, scf.x, shf.x), 0.0f);
            float m1 = fmaxf(fmaf(x1, scf.y, shf.y), 0.0f);
            __half2 hv = __floats2half2_rn(m0, m1);
            unsigned int hbits = *(unsigned int*)&hv;
            // skip exact-zero messages (agg only holds {+0, positive})
            if (dst >= 0 && hbits != 0u)
                unsafeAtomicAdd(agg + (size_t)dst * 64 + lane, hv);
        }
    }
}

// ---------------------------------------------------------------------------
// Node kernel (persistent): out = relu((agg+x)@W1+b1)@W2+b2 (+prev, relu opt)
// agg fp16; x_dst fp32 OR bf16; out fp32 OR bf16. 2 lgkm-barriers per tile.
// ---------------------------------------------------------------------------
__global__ __launch_bounds__(256)
void node_mfma_kernel(
    const __half2* __restrict__ agg,
    const float* __restrict__ xdf, const unsigned short* __restrict__ xdb,
    const short* __restrict__ pW1, const float* __restrict__ b1,
    const short* __restrict__ pW2, const float* __restrict__ b2,
    float* __restrict__ outf, unsigned short* __restrict__ outb,
    int N, int ntiles, int accumulate, int relu_out)
{
    __shared__ short sA[64 * 128];
    __shared__ short sH[64 * 128];

    const int t = threadIdx.x;
    const int lane = t & 63;
    const int w = t >> 6;
    const int l15 = lane & 15;
    const int l4 = lane >> 4;

    short8_t w1f[4][2], w2f[4][2];
    #pragma unroll
    for (int kk = 0; kk < 4; ++kk)
        #pragma unroll
        for (int p = 0; p < 2; ++p) {
            int nt = 2 * w + p;
            w1f[kk][p] = *(const short8_t*)&pW1[((kk * 8 + nt) * 64 + lane) * 8];
            w2f[kk][p] = *(const short8_t*)&pW2[((kk * 8 + nt) * 64 + lane) * 8];
        }
    float b1v[2], b2v[2];
    #pragma unroll
    for (int p = 0; p < 2; ++p) {
        int col = (2 * w + p) * 16 + l15;
        b1v[p] = b1[col];
        b2v[p] = b2[col];
    }

    for (int tile = blockIdx.x; tile < ntiles; tile += gridDim.x) {
        const int n0 = tile << 6;
        // --- stage A = bf16(fp16 agg + x_dst) ---
        #pragma unroll
        for (int i = 0; i < 4; ++i) {
            int idx = i * 256 + t;          // 64 rows x 16 chunks of 8 cols
            int row = idx >> 4, c8 = idx & 15;
            int gr = n0 + row; if (gr >= N) gr = N - 1;
            union { float4 f; __half2 h[4]; } ar;
            ar.f = ((const float4*)agg)[(size_t)gr * 16 + c8];
            float xv[8];
            if (xdf) {
                float4 x0 = ((const float4*)xdf)[(size_t)gr * 32 + c8 * 2];
                float4 x1 = ((const float4*)xdf)[(size_t)gr * 32 + c8 * 2 + 1];
                xv[0] = x0.x; xv[1] = x0.y; xv[2] = x0.z; xv[3] = x0.w;
                xv[4] = x1.x; xv[5] = x1.y; xv[6] = x1.z; xv[7] = x1.w;
            } else {
                uint4 xr = ((const uint4*)xdb)[(size_t)gr * 16 + c8];
                xv[0] = bs2f(xr.x & 0xffffu); xv[1] = bs2f(xr.x >> 16);
                xv[2] = bs2f(xr.y & 0xffffu); xv[3] = bs2f(xr.y >> 16);
                xv[4] = bs2f(xr.z & 0xffffu); xv[5] = bs2f(xr.z >> 16);
                xv[6] = bs2f(xr.w & 0xffffu); xv[7] = bs2f(xr.w >> 16);
            }
            short8_t v;
            #pragma unroll
            for (int j = 0; j < 4; ++j) {
                float2 a2 = __half22float2(ar.h[j]);
                v[2 * j]     = f2bs(a2.x + xv[2 * j]);
                v[2 * j + 1] = f2bs(a2.y + xv[2 * j + 1]);
            }
            int byte = row * 256 + ((c8 * 16) ^ ((row & 7) << 4));
            *(short8_t*)((char*)sA + byte) = v;
        }
        lds_barrier();

        // --- GEMM1 ---
        f32x4 acc[4][2];
        #pragma unroll
        for (int m = 0; m < 4; ++m) {
            acc[m][0] = (f32x4){0.f, 0.f, 0.f, 0.f};
            acc[m][1] = (f32x4){0.f, 0.f, 0.f, 0.f};
        }
        #pragma unroll
        for (int kk = 0; kk < 4; ++kk) {
            short8_t af[4];
            #pragma unroll
            for (int m = 0; m < 4; ++m) {
                int row = m * 16 + l15;
                int byte = row * 256 + ((kk * 64 + l4 * 16) ^ ((row & 7) << 4));
                af[m] = *(const short8_t*)((const char*)sA + byte);
            }
            #pragma unroll
            for (int m = 0; m < 4; ++m)
                #pragma unroll
                for (int p = 0; p < 2; ++p)
                    acc[m][p] = __builtin_amdgcn_mfma_f32_16x16x32_bf16(
                        af[m], w1f[kk][p], acc[m][p], 0, 0, 0);
        }
        #pragma unroll
        for (int m = 0; m < 4; ++m)
            #pragma unroll
            for (int p = 0; p < 2; ++p) {
                int col = (2 * w + p) * 16 + l15;
                #pragma unroll
                for (int r = 0; r < 4; ++r) {
                    int row = m * 16 + l4 * 4 + r;
                    short hs = f2bs(fmaxf(acc[m][p][r] + b1v[p], 0.f));
                    int byte = row * 256 + ((col * 2) ^ ((row & 7) << 4));
                    *(short*)((char*)sH + byte) = hs;
                }
            }
        lds_barrier();

        // --- GEMM2 ---
        f32x4 acc2[4][2];
        #pragma unroll
        for (int m = 0; m < 4; ++m) {
            acc2[m][0] = (f32x4){0.f, 0.f, 0.f, 0.f};
            acc2[m][1] = (f32x4){0.f, 0.f, 0.f, 0.f};
        }
        #pragma unroll
        for (int kk = 0; kk < 4; ++kk) {
            short8_t af[4];
            #pragma unroll
            for (int m = 0; m < 4; ++m) {
                int row = m * 16 + l15;
                int byte = row * 256 + ((kk * 64 + l4 * 16) ^ ((row & 7) << 4));
                af[m] = *(const short8_t*)((const char*)sH + byte);
            }
            #pragma unroll
            for (int m = 0; m < 4; ++m)
                #pragma unroll
                for (int p = 0; p < 2; ++p)
                    acc2[m][p] = __builtin_amdgcn_mfma_f32_16x16x32_bf16(
                        af[m], w2f[kk][p], acc2[m][p], 0, 0, 0);
        }
        // --- epilogue ---
        #pragma unroll
        for (int m = 0; m < 4; ++m)
            #pragma unroll
            for (int p = 0; p < 2; ++p) {
                int col = (2 * w + p) * 16 + l15;
                #pragma unroll
                for (int r = 0; r < 4; ++r) {
                    int row = n0 + m * 16 + l4 * 4 + r;
                    if (row < N) {
                        float v = acc2[m][p][r] + b2v[p];
                        if (outf) {
                            float* op = &outf[(size_t)row * 128 + col];
                            if (accumulate) v += *op;
                            if (relu_out) v = fmaxf(v, 0.f);
                            *op = v;
                        } else {
                            unsigned short* op = &outb[(size_t)row * 128 + col];
                            if (accumulate) v += bs2f((unsigned int)*op);
                            if (relu_out) v = fmaxf(v, 0.f);
                            *op = (unsigned short)f2bs(v);
                        }
                    }
                }
            }
    }
}

// ---------------------------------------------------------------------------
extern "C" void kernel_launch(void* const* d_in, const int* in_sizes, int n_in,
                              void* d_out, int out_size, void* d_ws, size_t ws_size,
                              hipStream_t stream)
{
    const float* x_lig   = (const float*)d_in[0];
    const float* x_pock  = (const float*)d_in[1];
    const int*   ei_bond = (const int*)d_in[2];
    const float* ew_bond = (const float*)d_in[3];
    const float* ea_bond = (const float*)d_in[4];
    const int*   ei_lp   = (const int*)d_in[5];
    const float* ew_lp   = (const float*)d_in[6];
    const float* ea_lp   = (const float*)d_in[7];
    const int*   ei_pl   = (const int*)d_in[8];
    const float* ew_pl   = (const float*)d_in[9];
    const float* ea_pl   = (const float*)d_in[10];
    const float* W0 = (const float*)d_in[11];
    const float* Wd = (const float*)d_in[12];
    const float* bd = (const float*)d_in[13];
    const float* We = (const float*)d_in[14];
    const float* be = (const float*)d_in[15];
    const float* W1 = (const float*)d_in[16];
    const float* b1 = (const float*)d_in[17];
    const float* W2 = (const float*)d_in[18];
    const float* b2 = (const float*)d_in[19];

    const int H = 128;
    const int N = in_sizes[0] / H;
    const int E_bond = in_sizes[3];
    const int E_lp   = in_sizes[6];
    const int E_pl   = in_sizes[9];

    // workspace: A,B,C bf16 activations; agg fp16; packed weights
    unsigned short* A  = (unsigned short*)d_ws;           // x_lig_bf -> lig0_bf
    unsigned short* Bb = A  + (size_t)N * H;              // x_pock_bf
    unsigned short* C  = Bb + (size_t)N * H;              // pock0_bf
    __half* agg = (__half*)(C + (size_t)N * H);           // N*128 fp16
    short* pWd  = (short*)(agg + (size_t)N * H);
    short* pW1s = pWd + 6 * 32768;
    short* pW2s = pW1s + 6 * 16384;
    float* Mb   = (float*)(pW2s + 6 * 16384);

    float* outL = (float*)d_out;
    float* outP = outL + (size_t)N * H;

    // Explicit grid caps: HW fits 2 edge blocks/CU (96KB LDS / 124 VGPR) and
    // 4 node blocks/CU (64KB LDS). The occupancy API under-reports (64KB
    // shared budget) — R6/R8 measured occupancy matched exactly 1 block/CU.
    const int capE = 2 * 256;
    const int capN = 4 * 256;

    tobf16_kernel<<<512, 256, 0, stream>>>(x_lig, x_pock, A, Bb, N * H / 4);
    pack_kernel<<<256, 256, 0, stream>>>(Wd, W1, W2, W0, We, pWd, pW1s, pW2s, Mb);

    const double start_d = exp(-5.0);
    const float rs    = (float)start_d;
    const float rstep = (float)((1.0 - start_d) / 127.0);
    const float rbeta = (float)std::pow(2.0 / 128.0 * (1.0 - start_d), -2.0);

    auto conv = [&](const unsigned short* src,
                    const float* xdf, const unsigned short* xdb,
                    const int* ei_, const float* ew_, const float* ea_, int E,
                    int l, int tt, float* outf, unsigned short* outb,
                    int accum, int relu) {
        hipMemsetAsync(agg, 0, (size_t)N * H * sizeof(__half), stream);
        const int lt = l * 3 + tt;
        const int ntE = (E + 63) / 64;
        const int gE = ntE < capE ? ntE : capE;
        edge_mfma_kernel<<<gE, 512, 0, stream>>>(
            src, ei_, ew_, ea_,
            pWd + (size_t)lt * 32768, bd + (size_t)lt * 256,
            Mb + (size_t)lt * 512, be + (size_t)lt * 128,
            (__half2*)agg, E, ntE, rs, rstep, rbeta);
        const int ntN = (N + 63) / 64;
        const int gN = ntN < capN ? ntN : capN;
        node_mfma_kernel<<<gN, 256, 0, stream>>>(
            (const __half2*)agg, xdf, xdb,
            pW1s + (size_t)lt * 16384, b1 + (size_t)lt * 128,
            pW2s + (size_t)lt * 16384, b2 + (size_t)lt * 128,
            outf, outb, N, ntN, accum, relu);
    };

    // layer 0 (order matters: A is overwritten by bond0's node after lp0+bond0 edges read it)
    conv(A,  x_pock, nullptr, ei_lp,   ew_lp,   ea_lp,   E_lp,   0, 1, nullptr, C, 0, 1);
    conv(A,  x_lig,  nullptr, ei_bond, ew_bond, ea_bond, E_bond, 0, 0, nullptr, A, 0, 0);
    conv(Bb, x_lig,  nullptr, ei_pl,   ew_pl,   ea_pl,   E_pl,   0, 2, nullptr, A, 1, 1);
    // layer 1: lig_bf = A, pock_bf = C
    conv(A, nullptr, A, ei_bond, ew_bond, ea_bond, E_bond, 1, 0, outL, nullptr, 0, 0);
    conv(C, nullptr, A, ei_pl,   ew_pl,   ea_pl,   E_pl,   1, 2, outL, nullptr, 1, 0);
    conv(A, nullptr, C, ei_lp,   ew_lp,   ea_lp,   E_lp,   1, 1, outP, nullptr, 0, 0);
}